// Round 1
// baseline (108.053 us; speedup 1.0000x reference)
//
#include <hip/hip_runtime.h>

// Problem dims (fixed by the reference)
#define B_    64
#define C_    8
#define FC_   16
#define WINS_ 30
#define TWIN_ 512
#define SE_   8
#define ALPHA_ 0.01f

#define NWIN_ (B_ * C_ * FC_ * WINS_)   // 245760 windows

// ---------------------------------------------------------------------------
// Kernel 1: per-window mean and max over TWIN=512 contiguous f32 samples.
// One wave (64 lanes) per window: 8 floats/lane via two coalesced float4
// loads, then a 6-step shuffle-xor tree reduce for sum and max.
// Memory-bound: reads 503 MB once; writes 2 x 245760 floats to workspace.
// ---------------------------------------------------------------------------
__global__ void win_reduce(const float* __restrict__ x,
                           float* __restrict__ wmean,
                           float* __restrict__ wmax) {
    const int tid    = blockIdx.x * blockDim.x + threadIdx.x;
    const int lane   = tid & 63;
    const int wave   = tid >> 6;
    const int nwaves = (gridDim.x * blockDim.x) >> 6;

    for (int w = wave; w < NWIN_; w += nwaves) {
        const float* base = x + (size_t)w * TWIN_;
        // two fully coalesced 1 KiB wave transactions
        const float4 a = *reinterpret_cast<const float4*>(base + lane * 4);
        const float4 b = *reinterpret_cast<const float4*>(base + 256 + lane * 4);

        float s = (a.x + a.y) + (a.z + a.w) + (b.x + b.y) + (b.z + b.w);
        float m = fmaxf(fmaxf(fmaxf(a.x, a.y), fmaxf(a.z, a.w)),
                        fmaxf(fmaxf(b.x, b.y), fmaxf(b.z, b.w)));

        #pragma unroll
        for (int off = 32; off >= 1; off >>= 1) {
            s += __shfl_xor(s, off, 64);
            m  = fmaxf(m, __shfl_xor(m, off, 64));
        }
        if (lane == 0) {
            wmean[w] = s * (1.0f / TWIN_);
            wmax[w]  = m;
        }
    }
}

// ---------------------------------------------------------------------------
// Kernel 2: one 64-thread block per (b,c). Variance across FC of the window
// means, SE bottleneck (leaky_relu + sigmoid), gated sum over window maxes.
// Tiny: 512 blocks x ~1 KB of data each.
// ---------------------------------------------------------------------------
__global__ void se_gate(const float* __restrict__ wmean,
                        const float* __restrict__ wmax,
                        const float* __restrict__ w1,   // (WINS, SE)
                        const float* __restrict__ b1,   // (SE,)
                        const float* __restrict__ w2,   // (SE, WINS)
                        const float* __restrict__ b2,   // (WINS,)
                        float* __restrict__ out) {      // (B, C, FC, 1)
    const int bc = blockIdx.x;      // 0 .. B*C-1
    const int t  = threadIdx.x;     // 0 .. 63

    __shared__ float s_mean[FC_ * WINS_];  // 480
    __shared__ float s_v[WINS_];
    __shared__ float s_h[SE_];
    __shared__ float s_g[WINS_];

    const float* mbase = wmean + (size_t)bc * (FC_ * WINS_);
    for (int i = t; i < FC_ * WINS_; i += 64) s_mean[i] = mbase[i];
    __syncthreads();

    // variance across features per window (ddof = 0)
    if (t < WINS_) {
        float mu = 0.f;
        #pragma unroll
        for (int f = 0; f < FC_; ++f) mu += s_mean[f * WINS_ + t];
        mu *= (1.0f / FC_);
        float var = 0.f;
        #pragma unroll
        for (int f = 0; f < FC_; ++f) {
            const float d = s_mean[f * WINS_ + t] - mu;
            var += d * d;
        }
        s_v[t] = var * (1.0f / FC_);
    }
    __syncthreads();

    // h = leaky_relu(v @ w1 + b1)
    if (t < SE_) {
        float acc = b1[t];
        #pragma unroll
        for (int w = 0; w < WINS_; ++w) acc += s_v[w] * w1[w * SE_ + t];
        s_h[t] = (acc >= 0.f) ? acc : ALPHA_ * acc;
    }
    __syncthreads();

    // g = sigmoid(h @ w2 + b2)
    if (t < WINS_) {
        float acc = b2[t];
        #pragma unroll
        for (int s = 0; s < SE_; ++s) acc += s_h[s] * w2[s * WINS_ + t];
        s_g[t] = 1.0f / (1.0f + expf(-acc));
    }
    __syncthreads();

    // out[f] = sum_w mx[f][w] * g[w]
    if (t < FC_) {
        const float* xbase = wmax + (size_t)bc * (FC_ * WINS_) + t * WINS_;
        float acc = 0.f;
        #pragma unroll
        for (int w = 0; w < WINS_; ++w) acc += xbase[w] * s_g[w];
        out[bc * FC_ + t] = acc;
    }
}

extern "C" void kernel_launch(void* const* d_in, const int* in_sizes, int n_in,
                              void* d_out, int out_size, void* d_ws, size_t ws_size,
                              hipStream_t stream) {
    const float* x  = (const float*)d_in[0];
    const float* w1 = (const float*)d_in[1];
    const float* b1 = (const float*)d_in[2];
    const float* w2 = (const float*)d_in[3];
    const float* b2 = (const float*)d_in[4];
    float* out = (float*)d_out;

    float* wmean = (float*)d_ws;
    float* wmax  = wmean + NWIN_;

    // Kernel 1: 2048 blocks x 256 threads = 8192 waves, 30 windows/wave.
    win_reduce<<<2048, 256, 0, stream>>>(x, wmean, wmax);
    // Kernel 2: one block per (b,c).
    se_gate<<<B_ * C_, 64, 0, stream>>>(wmean, wmax, w1, b1, w2, b2, out);
}

// Round 3
// 79.028 us; speedup vs baseline: 1.3673x; 1.3673x over previous
//
#include <hip/hip_runtime.h>

// Problem dims (fixed by the reference)
#define B_    64
#define C_    8
#define FC_   16
#define WINS_ 30
#define TWIN_ 512
#define SE_   8
#define ALPHA_ 0.01f

#define SLAB_  (FC_ * WINS_ * TWIN_)   // 245760 floats per (b,c)
#define NWBLK_ (FC_ * WINS_)           // 480 windows per (b,c)

// native clang vector type — accepted by __builtin_nontemporal_load
typedef float f4_t __attribute__((ext_vector_type(4)));

// ---------------------------------------------------------------------------
// Fully fused kernel: one block per (b,c).
//   Stage 1: stream the 983 KB slab; per-window mean+max into LDS.
//     240 tasks of 2 windows each; wave w does tasks w, w+16, ... (15 iters,
//     perfect balance). Within a wave, 32 lanes per window; each lane loads
//     4 float4 (16 floats), then a 5-step shfl_xor tree reduces BOTH windows
//     simultaneously (5 DS ops/window vs 12 for a full-wave tree).
//   Stage 2: variance over FC, SE bottleneck, gated sum — all in-block.
// ---------------------------------------------------------------------------
__global__ __launch_bounds__(1024) void fused_timeconv(
    const float* __restrict__ x,
    const float* __restrict__ w1,   // (WINS, SE)
    const float* __restrict__ b1,   // (SE,)
    const float* __restrict__ w2,   // (SE, WINS)
    const float* __restrict__ b2,   // (WINS,)
    float* __restrict__ out)        // (B, C, FC, 1)
{
    const int bc   = blockIdx.x;     // 0 .. 511
    const int t    = threadIdx.x;    // 0 .. 1023
    const int wv   = t >> 6;         // wave id 0..15
    const int lane = t & 63;
    const int sub  = lane >> 5;      // which of the 2 windows in this task
    const int il   = lane & 31;      // lane within the 32-lane window group

    __shared__ float s_mean[NWBLK_];
    __shared__ float s_max[NWBLK_];
    __shared__ float s_v[WINS_];
    __shared__ float s_h[SE_];
    __shared__ float s_g[WINS_];

    const float* slab = x + (size_t)bc * SLAB_;

    // ---- Stage 1: per-window mean & max -----------------------------------
    for (int j = wv; j < 240; j += 16) {
        // task j covers windows {2j, 2j+1} = floats [j*1024, j*1024+1024)
        const f4_t* p = reinterpret_cast<const f4_t*>(
            slab + j * 1024 + sub * 512 + il * 4);
        // 4 passes of 128 floats (32 lanes x float4); read-once -> nontemporal
        const f4_t a = __builtin_nontemporal_load(p);
        const f4_t b = __builtin_nontemporal_load(p + 32);
        const f4_t c = __builtin_nontemporal_load(p + 64);
        const f4_t d = __builtin_nontemporal_load(p + 96);

        float s = ((a.x + a.y) + (a.z + a.w)) + ((b.x + b.y) + (b.z + b.w))
                + ((c.x + c.y) + (c.z + c.w)) + ((d.x + d.y) + (d.z + d.w));
        float m = fmaxf(fmaxf(fmaxf(fmaxf(a.x, a.y), fmaxf(a.z, a.w)),
                              fmaxf(fmaxf(b.x, b.y), fmaxf(b.z, b.w))),
                        fmaxf(fmaxf(fmaxf(c.x, c.y), fmaxf(c.z, c.w)),
                              fmaxf(fmaxf(d.x, d.y), fmaxf(d.z, d.w))));

        // 5-step tree within each 32-lane group (offsets stay inside group)
        #pragma unroll
        for (int off = 16; off >= 1; off >>= 1) {
            s += __shfl_xor(s, off, 64);
            m  = fmaxf(m, __shfl_xor(m, off, 64));
        }
        if (il == 0) {
            const int w = j * 2 + sub;           // window index within block
            s_mean[w] = s * (1.0f / TWIN_);
            s_max[w]  = m;
        }
    }
    __syncthreads();

    // ---- Stage 2: SE path (tiny) ------------------------------------------
    // variance across features per window (ddof = 0)
    if (t < WINS_) {
        float mu = 0.f;
        #pragma unroll
        for (int f = 0; f < FC_; ++f) mu += s_mean[f * WINS_ + t];
        mu *= (1.0f / FC_);
        float var = 0.f;
        #pragma unroll
        for (int f = 0; f < FC_; ++f) {
            const float d = s_mean[f * WINS_ + t] - mu;
            var += d * d;
        }
        s_v[t] = var * (1.0f / FC_);
    }
    __syncthreads();

    // h = leaky_relu(v @ w1 + b1)
    if (t < SE_) {
        float acc = b1[t];
        #pragma unroll
        for (int w = 0; w < WINS_; ++w) acc += s_v[w] * w1[w * SE_ + t];
        s_h[t] = (acc >= 0.f) ? acc : ALPHA_ * acc;
    }
    __syncthreads();

    // g = sigmoid(h @ w2 + b2)
    if (t < WINS_) {
        float acc = b2[t];
        #pragma unroll
        for (int s = 0; s < SE_; ++s) acc += s_h[s] * w2[s * WINS_ + t];
        s_g[t] = 1.0f / (1.0f + expf(-acc));
    }
    __syncthreads();

    // out[f] = sum_w max[f][w] * g[w]
    if (t < FC_) {
        float acc = 0.f;
        #pragma unroll
        for (int w = 0; w < WINS_; ++w) acc += s_max[t * WINS_ + w] * s_g[w];
        out[bc * FC_ + t] = acc;
    }
}

extern "C" void kernel_launch(void* const* d_in, const int* in_sizes, int n_in,
                              void* d_out, int out_size, void* d_ws, size_t ws_size,
                              hipStream_t stream) {
    const float* x  = (const float*)d_in[0];
    const float* w1 = (const float*)d_in[1];
    const float* b1 = (const float*)d_in[2];
    const float* w2 = (const float*)d_in[3];
    const float* b2 = (const float*)d_in[4];
    float* out = (float*)d_out;

    fused_timeconv<<<B_ * C_, 1024, 0, stream>>>(x, w1, b1, w2, b2, out);
}